// Round 1
// baseline (486.474 us; speedup 1.0000x reference)
//
#include <hip/hip_runtime.h>
#include <hip/hip_bf16.h>
#include <cstdint>
#include <cstddef>

#define V_TEXT   256
#define V_TOTAL  4352
#define V_AUDIO  4096
#define B_       8
#define H_       4
#define TQ_      800
#define TK_      128
#define T_TOK    1024
#define NSEQ     32          // B_*H_
#define NEGF     (-1.0e9f)
#define CH       16          // recursion prefetch chunk (timesteps)

// ---------- log-add-exp helpers (match jnp.logaddexp with finite -1e9) ----------
__device__ __forceinline__ float lae2(float a, float b) {
    float m = fmaxf(a, b);
    float d = fminf(a, b) - m;            // <= 0; 0 when equal -> +ln2, matches jnp
    return m + __logf(1.0f + __expf(d));
}
__device__ __forceinline__ float lae3(float a, float b, float c) {
    float m = fmaxf(fmaxf(a, b), c);
    float s = __expf(a - m) + __expf(b - m) + __expf(c - m);
    return m + __logf(s);
}

// ---------- Kernel 1: per-row CE nll (log_softmax over audio vocab) ----------
// one block per (b,t) row; 16 elems/thread kept in registers -> single HBM pass
__global__ __launch_bounds__(256) void ce_kernel(
    const float* __restrict__ logits, const int* __restrict__ targets,
    const int* __restrict__ alens, float* __restrict__ nll_out)
{
    __shared__ float red[4];
    int row = blockIdx.x;
    int tid = threadIdx.x;
    const float* p = logits + (size_t)row * V_TOTAL + V_TEXT;

    float4 v[4];
    float m = -1e30f;
    #pragma unroll
    for (int i = 0; i < 4; i++) {
        v[i] = *reinterpret_cast<const float4*>(p + tid * 4 + i * 1024);
        m = fmaxf(m, fmaxf(fmaxf(v[i].x, v[i].y), fmaxf(v[i].z, v[i].w)));
    }
    #pragma unroll
    for (int off = 32; off > 0; off >>= 1) m = fmaxf(m, __shfl_xor(m, off));
    int wv = tid >> 6;
    if ((tid & 63) == 0) red[wv] = m;
    __syncthreads();
    m = fmaxf(fmaxf(red[0], red[1]), fmaxf(red[2], red[3]));
    __syncthreads();                       // protect red[] before reuse for sums

    float s = 0.0f;
    #pragma unroll
    for (int i = 0; i < 4; i++)
        s += __expf(v[i].x - m) + __expf(v[i].y - m) +
             __expf(v[i].z - m) + __expf(v[i].w - m);
    #pragma unroll
    for (int off = 32; off > 0; off >>= 1) s += __shfl_xor(s, off);
    if ((tid & 63) == 0) red[wv] = s;
    __syncthreads();

    if (tid == 0) {
        s = red[0] + red[1] + red[2] + red[3];
        float lse = m + __logf(s);
        int tg = targets[row];
        int b = row >> 10, t = row & (T_TOK - 1);
        bool valid = (t < alens[b]) && (tg != -100);
        float nll = 0.0f;
        if (valid) {
            int idx = min(max(tg - V_TEXT, 0), V_AUDIO - 1);
            nll = lse - p[idx];
        }
        nll_out[row] = nll;
    }
}

// ---------- Kernel 2a: per-(n,t) masked logsumexp over Tk+1 classes ----------
// class 0 = blank (-8.0), class j (1..k) = attn[...,j-1]; j>k excluded.
// 4 waves/block, one row per wave; lane l holds cols 2l,2l+1 (float2).
__global__ __launch_bounds__(256) void lse_kernel(
    const float* __restrict__ attn, const int* __restrict__ src_lens,
    float* __restrict__ lse_out)
{
    int w = threadIdx.x >> 6, lane = threadIdx.x & 63;
    int t = blockIdx.x * 4 + w;
    int n = blockIdx.y;
    int k = min(src_lens[n >> 2], TK_);

    const float2 x = *reinterpret_cast<const float2*>(
        attn + ((size_t)n * TQ_ + t) * TK_ + 2 * lane);
    int j0 = 2 * lane + 1, j1 = 2 * lane + 2;

    float m = (lane == 0) ? -8.0f : -1e30f;
    if (j0 <= k) m = fmaxf(m, x.x);
    if (j1 <= k) m = fmaxf(m, x.y);
    #pragma unroll
    for (int off = 32; off > 0; off >>= 1) m = fmaxf(m, __shfl_xor(m, off));

    float s = (lane == 0) ? __expf(-8.0f - m) : 0.0f;
    if (j0 <= k) s += __expf(x.x - m);
    if (j1 <= k) s += __expf(x.y - m);
    #pragma unroll
    for (int off = 32; off > 0; off >>= 1) s += __shfl_xor(s, off);

    if (lane == 0) lse_out[n * TQ_ + t] = m + __logf(s);
}

// ---------- Kernel 2b: CTC forward recursion, one wave per sequence ----------
// lane l owns states 4l..4l+3; lane 63 additionally owns state 256.
// Only cross-lane need per step: alpha[4l-1] -> single __shfl_up.
// Emits for lane l's odd states are attn[t][2l], attn[t][2l+1] (float2/lane).
__global__ __launch_bounds__(64) void rec_kernel(
    const float* __restrict__ attn, const float* __restrict__ lse,
    const int* __restrict__ src_lens, const int* __restrict__ out_lens,
    float* __restrict__ loss_out)
{
    int n = blockIdx.x;
    int lane = threadIdx.x;
    int k = min(src_lens[n >> 2], TK_);
    int q = min(out_lens[n >> 2], TQ_);
    const float* base = attn + (size_t)n * TQ_ * TK_;
    const float* lrow = lse + n * TQ_;

    int s0 = lane * 4;
    int smax = 2 * k;                       // states s <= 2k are ext_valid
    bool v0 = (s0     <= smax);
    bool v1 = (s0 + 1 <= smax);
    bool v2 = (s0 + 2 <= smax);
    bool v3 = (s0 + 3 <= smax);
    bool v4 = (lane == 63) && (256 <= smax);

    float2 xb[CH], xn[CH];
    float  lb[CH], ln_[CH];

    #pragma unroll
    for (int i = 0; i < CH; i++) {
        xb[i] = *reinterpret_cast<const float2*>(base + (size_t)i * TK_ + 2 * lane);
        lb[i] = lrow[i];
    }

    float a0, a1, a2, a3, a4;
    {   // t = 0 init: alpha0[0]=emit(blank), alpha0[1]=emit(label1), rest NEG
        float l0 = lb[0];
        a0 = (lane == 0) ? (-8.0f - l0)   : NEGF;
        a1 = (lane == 0) ? (xb[0].x - l0) : NEGF;
        a2 = NEGF; a3 = NEGF; a4 = NEGF;
        if (!v0) a0 = NEGF;
        if (!v1) a1 = NEGF;
    }

    for (int cb = 0; cb < q; cb += CH) {
        int nb = cb + CH;
        #pragma unroll
        for (int i = 0; i < CH; i++) {      // prefetch next chunk (clamped)
            int tt = min(nb + i, TQ_ - 1);
            xn[i]  = *reinterpret_cast<const float2*>(base + (size_t)tt * TK_ + 2 * lane);
            ln_[i] = lrow[tt];
        }
        #pragma unroll
        for (int i = 0; i < CH; i++) {
            int t = cb + i;
            if (t >= 1 && t < q) {          // uniform branch (q uniform per block)
                float2 x = xb[i];
                float ls = lb[i];
                float p3 = __shfl_up(a3, 1);        // alpha[4l-1]
                if (lane == 0) p3 = NEGF;
                float eb = -8.0f - ls;              // blank emit
                float n0 = lae2(a0, p3) + eb;                   // s=4l   (even)
                float n1 = lae3(a1, a0, p3) + (x.x - ls);       // s=4l+1 (odd, skip)
                float n2 = lae2(a2, a1) + eb;                   // s=4l+2 (even)
                float n3 = lae3(a3, a2, a1) + (x.y - ls);       // s=4l+3 (odd, skip)
                float n4 = lae2(a4, a3) + eb;                   // s=256  (lane63)
                a0 = v0 ? n0 : NEGF;
                a1 = v1 ? n1 : NEGF;
                a2 = v2 ? n2 : NEGF;
                a3 = v3 ? n3 : NEGF;
                a4 = v4 ? n4 : NEGF;
            }
        }
        #pragma unroll
        for (int i = 0; i < CH; i++) { xb[i] = xn[i]; lb[i] = ln_[i]; }
    }

    // gather alpha[2k-1], alpha[2k]
    int s1 = 2 * k - 1;
    int s2 = 2 * k;
    float e1, e2;
    {
        int l = s1 >> 2, r = s1 & 3;        // s1 odd -> r in {1,3}
        float c1 = __shfl(a1, l), c3 = __shfl(a3, l);
        e1 = (r == 1) ? c1 : c3;
    }
    if (s2 == 256) {
        e2 = __shfl(a4, 63);
    } else {
        int l = s2 >> 2, r = s2 & 3;        // s2 even -> r in {0,2}
        float c0 = __shfl(a0, l), c2 = __shfl(a2, l);
        e2 = (r == 0) ? c0 : c2;
    }
    float nll = -lae2(e1, e2);
    float loss = nll / (float)k;
    if (!(isfinite(loss) && loss < 1.0e8f)) loss = 0.0f;
    if (lane == 0) loss_out[n] = loss;
}

// ---------- Kernel 3: finalize ----------
__global__ __launch_bounds__(256) void fin_kernel(
    const float* __restrict__ nll, const int* __restrict__ alens,
    const int* __restrict__ step, const float* __restrict__ attn_losses,
    float* __restrict__ out)
{
    __shared__ float red[4];
    int tid = threadIdx.x;
    float s = 0.0f;
    for (int i = tid; i < B_ * T_TOK; i += 256) s += nll[i];
    #pragma unroll
    for (int off = 32; off > 0; off >>= 1) s += __shfl_xor(s, off);
    if ((tid & 63) == 0) red[tid >> 6] = s;
    __syncthreads();
    if (tid == 0) {
        float ce_sum = red[0] + red[1] + red[2] + red[3];
        int denom = 0;
        for (int b = 0; b < B_; b++) denom += min(alens[b], T_TOK);
        denom = max(denom, 1);
        float token = ce_sum / (float)denom;
        float a = 0.0f;
        for (int i = 0; i < NSEQ; i++) a += attn_losses[i];
        a *= (1.0f / NSEQ);
        if (step[0] <= 5000) a = 0.0f;       // ATTN_START gate (dynamic)
        out[0] = 1.5f * token + 10.0f * a;   // total
        out[1] = a;                          // attn_loss
        out[2] = token;                      // token_loss
    }
}

extern "C" void kernel_launch(void* const* d_in, const int* in_sizes, int n_in,
                              void* d_out, int out_size, void* d_ws, size_t ws_size,
                              hipStream_t stream)
{
    const float* logits  = (const float*)d_in[0];
    const float* attn    = (const float*)d_in[1];
    const int*   targets = (const int*)d_in[2];
    const int*   alens   = (const int*)d_in[3];
    const int*   slens   = (const int*)d_in[4];
    const int*   olens   = (const int*)d_in[5];
    const int*   step    = (const int*)d_in[6];
    float* out = (float*)d_out;
    float* ws  = (float*)d_ws;

    // ws layout (floats): [0..31] per-seq attn losses | [64..25663] lse | [25728..33919] per-row nll
    float* ws_attn = ws;
    float* ws_lse  = ws + 64;
    float* ws_nll  = ws + 25728;

    ce_kernel <<<dim3(B_ * T_TOK),       dim3(256), 0, stream>>>(logits, targets, alens, ws_nll);
    lse_kernel<<<dim3(TQ_ / 4, NSEQ),    dim3(256), 0, stream>>>(attn, slens, ws_lse);
    rec_kernel<<<dim3(NSEQ),             dim3(64),  0, stream>>>(attn, ws_lse, slens, olens, ws_attn);
    fin_kernel<<<dim3(1),                dim3(256), 0, stream>>>(ws_nll, alens, step, ws_attn, out);
}

// Round 3
// 418.877 us; speedup vs baseline: 1.1614x; 1.1614x over previous
//
#include <hip/hip_runtime.h>
#include <hip/hip_bf16.h>
#include <cstdint>
#include <cstddef>

#define V_TEXT   256
#define V_TOTAL  4352
#define V_AUDIO  4096
#define B_       8
#define H_       4
#define TQ_      800
#define TK_      128
#define T_TOK    1024
#define NSEQ     32
#define NEGF     (-1.0e9f)
#define K2       1.4426950408889634f   // 1/ln2
#define LN2      0.6931471805599453f

// base-2 logaddexp: same real-math result as natural logaddexp after
// pre-scaling inputs by 1/ln2 and post-scaling by ln2. v_exp/v_log are
// natively base-2 on gfx950 -> saves per-op scale muls on the chain.
__device__ __forceinline__ float lae2_2(float a, float b) {
    float m = fmaxf(a, b);
    float d = fminf(a, b) - m;            // <= 0; both-equal -> +1 (=-log2 .5)
    return m + __builtin_log2f(1.0f + __builtin_exp2f(d));
}

// ---------- Kernel 1: per-row CE nll, one wave per row ----------
__global__ __launch_bounds__(256) void ce_kernel(
    const float* __restrict__ logits, const int* __restrict__ targets,
    const int* __restrict__ alens, float* __restrict__ nll_out)
{
    int w = threadIdx.x >> 6, lane = threadIdx.x & 63;
    int row = blockIdx.x * 4 + w;
    const float* p = logits + (size_t)row * V_TOTAL + V_TEXT;

    float4 v0 = *reinterpret_cast<const float4*>(p + lane * 4);
    float4 v1 = *reinterpret_cast<const float4*>(p + lane * 4 + 1024);
    float4 v2 = *reinterpret_cast<const float4*>(p + lane * 4 + 2048);
    float4 v3 = *reinterpret_cast<const float4*>(p + lane * 4 + 3072);
    int tg = targets[row];

    float m = fmaxf(fmaxf(fmaxf(v0.x, v0.y), fmaxf(v0.z, v0.w)),
                    fmaxf(fmaxf(v1.x, v1.y), fmaxf(v1.z, v1.w)));
    m = fmaxf(m, fmaxf(fmaxf(v2.x, v2.y), fmaxf(v2.z, v2.w)));
    m = fmaxf(m, fmaxf(fmaxf(v3.x, v3.y), fmaxf(v3.z, v3.w)));
    #pragma unroll
    for (int off = 32; off > 0; off >>= 1) m = fmaxf(m, __shfl_xor(m, off));

    float s = __expf(v0.x - m) + __expf(v0.y - m) + __expf(v0.z - m) + __expf(v0.w - m)
            + __expf(v1.x - m) + __expf(v1.y - m) + __expf(v1.z - m) + __expf(v1.w - m)
            + __expf(v2.x - m) + __expf(v2.y - m) + __expf(v2.z - m) + __expf(v2.w - m)
            + __expf(v3.x - m) + __expf(v3.y - m) + __expf(v3.z - m) + __expf(v3.w - m);
    #pragma unroll
    for (int off = 32; off > 0; off >>= 1) s += __shfl_xor(s, off);

    if (lane == 0) {
        float lse = m + __logf(s);
        int b = row >> 10, t = row & (T_TOK - 1);
        bool valid = (t < alens[b]) && (tg != -100);
        float nll = 0.0f;
        if (valid) {
            int idx = min(max(tg - V_TEXT, 0), V_AUDIO - 1);
            nll = lse - p[idx];
        }
        nll_out[row] = nll;
    }
}

// ---------- Kernel 2a: per-(n,t) masked logsumexp over Tk+1 classes ----------
__global__ __launch_bounds__(256) void lse_kernel(
    const float* __restrict__ attn, const int* __restrict__ src_lens,
    float* __restrict__ lse_out)
{
    int w = threadIdx.x >> 6, lane = threadIdx.x & 63;
    int t = blockIdx.x * 4 + w;
    int n = blockIdx.y;
    int k = min(src_lens[n >> 2], TK_);

    const float2 x = *reinterpret_cast<const float2*>(
        attn + ((size_t)n * TQ_ + t) * TK_ + 2 * lane);
    int j0 = 2 * lane + 1, j1 = 2 * lane + 2;

    float m = (lane == 0) ? -8.0f : -1e30f;
    if (j0 <= k) m = fmaxf(m, x.x);
    if (j1 <= k) m = fmaxf(m, x.y);
    #pragma unroll
    for (int off = 32; off > 0; off >>= 1) m = fmaxf(m, __shfl_xor(m, off));

    float s = (lane == 0) ? __expf(-8.0f - m) : 0.0f;
    if (j0 <= k) s += __expf(x.x - m);
    if (j1 <= k) s += __expf(x.y - m);
    #pragma unroll
    for (int off = 32; off > 0; off >>= 1) s += __shfl_xor(s, off);

    if (lane == 0) lse_out[n * TQ_ + t] = m + __logf(s);
}

// ---------- Kernel 2b: CTC forward recursion, one wave per sequence ----------
// lane l owns states 4l..4l+3 (lane 63 also 256). Log2 domain.
// Explicit named-register 8-deep prefetch pipeline (NO arrays -> no scratch).
// Shuffle of new a3 issued at end of step t, consumed at t+1.
__global__ __launch_bounds__(64) void rec_kernel(
    const float* __restrict__ attn, const float* __restrict__ lse,
    const int* __restrict__ src_lens, const int* __restrict__ out_lens,
    float* __restrict__ loss_out)
{
    int n = blockIdx.x;
    int lane = threadIdx.x;
    int k = min(src_lens[n >> 2], TK_);
    int q = min(out_lens[n >> 2], TQ_);
    const float* base = attn + (size_t)n * TQ_ * TK_;
    const float* lrow = lse + n * TQ_;
    const float* xp = base + 2 * lane;

    int s0 = lane * 4;
    int smax = 2 * k;
    bool v0 = (s0     <= smax);
    bool v1 = (s0 + 1 <= smax);
    bool v2 = (s0 + 2 <= smax);
    bool v3 = (s0 + 3 <= smax);
    bool v4 = (lane == 63) && (256 <= smax);

    // preload pipeline slots t = 0..7 (named scalars only)
    float2 x0 = *reinterpret_cast<const float2*>(xp + 0 * TK_);
    float2 x1 = *reinterpret_cast<const float2*>(xp + 1 * TK_);
    float2 x2 = *reinterpret_cast<const float2*>(xp + 2 * TK_);
    float2 x3 = *reinterpret_cast<const float2*>(xp + 3 * TK_);
    float2 x4 = *reinterpret_cast<const float2*>(xp + 4 * TK_);
    float2 x5 = *reinterpret_cast<const float2*>(xp + 5 * TK_);
    float2 x6 = *reinterpret_cast<const float2*>(xp + 6 * TK_);
    float2 x7 = *reinterpret_cast<const float2*>(xp + 7 * TK_);
    float l0 = lrow[0], l1 = lrow[1], l2 = lrow[2], l3 = lrow[3];
    float l4 = lrow[4], l5 = lrow[5], l6 = lrow[6], l7 = lrow[7];

    float a0, a1, a2, a3, a4, p3;
    a0 = (lane == 0) ? (-8.0f - l0) * K2   : NEGF;
    a1 = (lane == 0) ? (x0.x  - l0) * K2   : NEGF;
    a2 = NEGF; a3 = NEGF; a4 = NEGF; p3 = NEGF;
    if (!v0) a0 = NEGF;
    if (!v1) a1 = NEGF;

#define STEP(i)                                                               \
    do {                                                                      \
        int t = t0 + (i);                                                     \
        float2 xv = x##i; float lv = l##i;                                    \
        int tp = min(t + 8, TQ_ - 1);                                         \
        x##i = *reinterpret_cast<const float2*>(xp + (size_t)tp * TK_);       \
        l##i = lrow[tp];                                                      \
        if (t >= 1 && t < q) {                                                \
            float e0 = (xv.x - lv) * K2;                                      \
            float e1 = (xv.y - lv) * K2;                                      \
            float eb = (-8.0f - lv) * K2;                                     \
            float c01 = lae2_2(a0, p3);    /* shared by n0, n1 */             \
            float c12 = lae2_2(a2, a1);    /* shared by n2, n3 */             \
            float n4  = lae2_2(a4, a3) + eb;                                  \
            float n0  = c01 + eb;                                             \
            float n1  = lae2_2(a1, c01) + e0;                                 \
            float n2  = c12 + eb;                                             \
            float n3  = lae2_2(a3, c12) + e1;                                 \
            a0 = v0 ? n0 : NEGF;                                              \
            a1 = v1 ? n1 : NEGF;                                              \
            a2 = v2 ? n2 : NEGF;                                              \
            a3 = v3 ? n3 : NEGF;                                              \
            a4 = v4 ? n4 : NEGF;                                              \
            p3 = __shfl_up(a3, 1);         /* consumed next step */           \
            if (lane == 0) p3 = NEGF;                                         \
        }                                                                     \
    } while (0)

    for (int t0 = 0; t0 < q; t0 += 8) {
        STEP(0); STEP(1); STEP(2); STEP(3);
        STEP(4); STEP(5); STEP(6); STEP(7);
    }
#undef STEP

    // gather alpha[2k-1], alpha[2k] (log2 domain)
    int s1 = 2 * k - 1;
    int s2 = 2 * k;
    float e1v, e2v;
    {
        int l = s1 >> 2, r = s1 & 3;
        float c1 = __shfl(a1, l), c3 = __shfl(a3, l);
        e1v = (r == 1) ? c1 : c3;
    }
    if (s2 == 256) {
        e2v = __shfl(a4, 63);
    } else {
        int l = s2 >> 2, r = s2 & 3;
        float c0 = __shfl(a0, l), c2 = __shfl(a2, l);
        e2v = (r == 0) ? c0 : c2;
    }
    float nll = -lae2_2(e1v, e2v) * LN2;   // back to nats
    float loss = nll / (float)k;
    if (!(isfinite(loss) && loss < 1.0e8f)) loss = 0.0f;
    if (lane == 0) loss_out[n] = loss;
}

// ---------- Kernel 3: finalize ----------
__global__ __launch_bounds__(256) void fin_kernel(
    const float* __restrict__ nll, const int* __restrict__ alens,
    const int* __restrict__ step, const float* __restrict__ attn_losses,
    float* __restrict__ out)
{
    __shared__ float red[4];
    int tid = threadIdx.x;
    float s = 0.0f;
    for (int i = tid; i < B_ * T_TOK; i += 256) s += nll[i];
    #pragma unroll
    for (int off = 32; off > 0; off >>= 1) s += __shfl_xor(s, off);
    if ((tid & 63) == 0) red[tid >> 6] = s;
    __syncthreads();
    if (tid == 0) {
        float ce_sum = red[0] + red[1] + red[2] + red[3];
        int denom = 0;
        for (int b = 0; b < B_; b++) denom += min(alens[b], T_TOK);
        denom = max(denom, 1);
        float token = ce_sum / (float)denom;
        float a = 0.0f;
        for (int i = 0; i < NSEQ; i++) a += attn_losses[i];
        a *= (1.0f / NSEQ);
        if (step[0] <= 5000) a = 0.0f;
        out[0] = 1.5f * token + 10.0f * a;
        out[1] = a;
        out[2] = token;
    }
}

extern "C" void kernel_launch(void* const* d_in, const int* in_sizes, int n_in,
                              void* d_out, int out_size, void* d_ws, size_t ws_size,
                              hipStream_t stream)
{
    const float* logits  = (const float*)d_in[0];
    const float* attn    = (const float*)d_in[1];
    const int*   targets = (const int*)d_in[2];
    const int*   alens   = (const int*)d_in[3];
    const int*   slens   = (const int*)d_in[4];
    const int*   olens   = (const int*)d_in[5];
    const int*   step    = (const int*)d_in[6];
    float* out = (float*)d_out;
    float* ws  = (float*)d_ws;

    float* ws_attn = ws;            // [0..31]
    float* ws_lse  = ws + 64;       // [64 .. 64+25600)
    float* ws_nll  = ws + 25728;    // [25728 .. +8192)

    ce_kernel <<<dim3(B_ * T_TOK / 4), dim3(256), 0, stream>>>(logits, targets, alens, ws_nll);
    lse_kernel<<<dim3(TQ_ / 4, NSEQ),  dim3(256), 0, stream>>>(attn, slens, ws_lse);
    rec_kernel<<<dim3(NSEQ),           dim3(64),  0, stream>>>(attn, ws_lse, slens, olens, ws_attn);
    fin_kernel<<<dim3(1),              dim3(256), 0, stream>>>(ws_nll, alens, step, ws_attn, out);
}

// Round 5
// 403.463 us; speedup vs baseline: 1.2057x; 1.0382x over previous
//
#include <hip/hip_runtime.h>
#include <hip/hip_bf16.h>
#include <cstdint>
#include <cstddef>

#define V_TEXT   256
#define V_TOTAL  4352
#define V_AUDIO  4096
#define B_       8
#define H_       4
#define TQ_      800
#define TK_      128
#define T_TOK    1024
#define NSEQ     32
#define NEGF     (-1.0e9f)
#define K2       1.4426950408889634f   // 1/ln2
#define LN2      0.6931471805599453f
#define EB8      11.541560327111707f   // 8*K2
#define FNEGINF  (-3.0e38f)

// ---- DPP helpers (VALU cross-lane, no LDS latency). ctrl must be ICE. ----
template <int CTRL>
__device__ __forceinline__ float dpp_mov(float x, float old) {
    return __int_as_float(__builtin_amdgcn_update_dpp(
        __float_as_int(old), __float_as_int(x), CTRL, 0xf, 0xf, false));
}
__device__ __forceinline__ float dpp_shr1_old(float x, float old) {
    // lane i <- lane i-1; lane 0 <- old   (wave_shr:1 = 0x138)
    return dpp_mov<0x138>(x, old);
}
__device__ __forceinline__ float lane_bcast(float x, int lane) {
    return __int_as_float(__builtin_amdgcn_readlane(__float_as_int(x), lane));
}
// full-wave reductions: row_shr 1/2/4/8 then row_bcast15/31; total lands in
// lane 63, broadcast back via readlane. identity-old keeps boundaries clean.
__device__ __forceinline__ float wave_max(float x) {
    x = fmaxf(x, dpp_mov<0x111>(x, FNEGINF));
    x = fmaxf(x, dpp_mov<0x112>(x, FNEGINF));
    x = fmaxf(x, dpp_mov<0x114>(x, FNEGINF));
    x = fmaxf(x, dpp_mov<0x118>(x, FNEGINF));
    x = fmaxf(x, dpp_mov<0x142>(x, FNEGINF));
    x = fmaxf(x, dpp_mov<0x143>(x, FNEGINF));
    return lane_bcast(x, 63);
}
__device__ __forceinline__ float wave_sum(float x) {
    x += dpp_mov<0x111>(x, 0.0f);
    x += dpp_mov<0x112>(x, 0.0f);
    x += dpp_mov<0x114>(x, 0.0f);
    x += dpp_mov<0x118>(x, 0.0f);
    x += dpp_mov<0x142>(x, 0.0f);
    x += dpp_mov<0x143>(x, 0.0f);
    return lane_bcast(x, 63);
}

// base-2 logaddexp (inputs already in log2 domain)
__device__ __forceinline__ float lae2_2(float a, float b) {
    float m = fmaxf(a, b);
    float d = fminf(a, b) - m;
    return m + __builtin_log2f(1.0f + __builtin_exp2f(d));
}

// ---------- Kernel 1: per-row CE nll, one wave per row ----------
__global__ __launch_bounds__(256) void ce_kernel(
    const float* __restrict__ logits, const int* __restrict__ targets,
    const int* __restrict__ alens, float* __restrict__ nll_out)
{
    int w = threadIdx.x >> 6, lane = threadIdx.x & 63;
    int row = blockIdx.x * 4 + w;
    const float* p = logits + (size_t)row * V_TOTAL + V_TEXT;

    float4 v0 = *reinterpret_cast<const float4*>(p + lane * 4);
    float4 v1 = *reinterpret_cast<const float4*>(p + lane * 4 + 1024);
    float4 v2 = *reinterpret_cast<const float4*>(p + lane * 4 + 2048);
    float4 v3 = *reinterpret_cast<const float4*>(p + lane * 4 + 3072);
    int tg = targets[row];

    float m = fmaxf(fmaxf(fmaxf(v0.x, v0.y), fmaxf(v0.z, v0.w)),
                    fmaxf(fmaxf(v1.x, v1.y), fmaxf(v1.z, v1.w)));
    m = fmaxf(m, fmaxf(fmaxf(v2.x, v2.y), fmaxf(v2.z, v2.w)));
    m = fmaxf(m, fmaxf(fmaxf(v3.x, v3.y), fmaxf(v3.z, v3.w)));
    m = wave_max(m);

    float mn = -m * K2;   // exp(v-m) = exp2(v*K2 - m*K2)
    float s =
      __builtin_exp2f(__builtin_fmaf(v0.x,K2,mn)) + __builtin_exp2f(__builtin_fmaf(v0.y,K2,mn))
    + __builtin_exp2f(__builtin_fmaf(v0.z,K2,mn)) + __builtin_exp2f(__builtin_fmaf(v0.w,K2,mn))
    + __builtin_exp2f(__builtin_fmaf(v1.x,K2,mn)) + __builtin_exp2f(__builtin_fmaf(v1.y,K2,mn))
    + __builtin_exp2f(__builtin_fmaf(v1.z,K2,mn)) + __builtin_exp2f(__builtin_fmaf(v1.w,K2,mn))
    + __builtin_exp2f(__builtin_fmaf(v2.x,K2,mn)) + __builtin_exp2f(__builtin_fmaf(v2.y,K2,mn))
    + __builtin_exp2f(__builtin_fmaf(v2.z,K2,mn)) + __builtin_exp2f(__builtin_fmaf(v2.w,K2,mn))
    + __builtin_exp2f(__builtin_fmaf(v3.x,K2,mn)) + __builtin_exp2f(__builtin_fmaf(v3.y,K2,mn))
    + __builtin_exp2f(__builtin_fmaf(v3.z,K2,mn)) + __builtin_exp2f(__builtin_fmaf(v3.w,K2,mn));
    s = wave_sum(s);

    if (lane == 0) {
        float lse = m + __builtin_log2f(s) * LN2;
        int b = row >> 10, t = row & (T_TOK - 1);
        bool valid = (t < alens[b]) && (tg != -100);
        float nll = 0.0f;
        if (valid) {
            int idx = min(max(tg - V_TEXT, 0), V_AUDIO - 1);
            nll = lse - p[idx];
        }
        nll_out[row] = nll;
    }
}

// ---------- Kernel 2a: per-(n,t) masked logsumexp; outputs Lneg = -lse*K2 ----------
__global__ __launch_bounds__(256) void lse_kernel(
    const float* __restrict__ attn, const int* __restrict__ src_lens,
    float* __restrict__ lneg_out)
{
    int w = threadIdx.x >> 6, lane = threadIdx.x & 63;
    int t = blockIdx.x * 4 + w;
    int n = blockIdx.y;
    int k = min(src_lens[n >> 2], TK_);

    const float2 x = *reinterpret_cast<const float2*>(
        attn + ((size_t)n * TQ_ + t) * TK_ + 2 * lane);
    float xx = x.x * K2, xy = x.y * K2;   // log2 domain
    int j0 = 2 * lane + 1, j1 = 2 * lane + 2;

    float m = (lane == 0) ? -EB8 : FNEGINF;
    if (j0 <= k) m = fmaxf(m, xx);
    if (j1 <= k) m = fmaxf(m, xy);
    m = wave_max(m);

    float s = (lane == 0) ? __builtin_exp2f(-EB8 - m) : 0.0f;
    if (j0 <= k) s += __builtin_exp2f(xx - m);
    if (j1 <= k) s += __builtin_exp2f(xy - m);
    s = wave_sum(s);

    if (lane == 0) lneg_out[n * TQ_ + t] = -(m + __builtin_log2f(s));
}

// ---------- Kernel 2b: CTC forward recursion, one wave per sequence ----------
// lane l owns states 4l..4l+3 (lane 63 also 256), log2 domain.
// DPP wave_shr:1 for the single cross-lane dep; no validity masks needed
// (info flows only from lower states; gathered states are always valid).
__global__ __launch_bounds__(64) void rec_kernel(
    const float* __restrict__ attn, const float* __restrict__ lneg,
    const int* __restrict__ src_lens, const int* __restrict__ out_lens,
    float* __restrict__ loss_out)
{
    int n = blockIdx.x;
    int lane = threadIdx.x;
    int k = min(src_lens[n >> 2], TK_);
    int q = min(out_lens[n >> 2], TQ_);
    const float* xp = attn + (size_t)n * TQ_ * TK_ + 2 * lane;
    const float* lrow = lneg + n * TQ_;

    // preload pipeline slots t = 0..7 (named scalars only)
    float2 x0 = *reinterpret_cast<const float2*>(xp + 0 * TK_);
    float2 x1 = *reinterpret_cast<const float2*>(xp + 1 * TK_);
    float2 x2 = *reinterpret_cast<const float2*>(xp + 2 * TK_);
    float2 x3 = *reinterpret_cast<const float2*>(xp + 3 * TK_);
    float2 x4 = *reinterpret_cast<const float2*>(xp + 4 * TK_);
    float2 x5 = *reinterpret_cast<const float2*>(xp + 5 * TK_);
    float2 x6 = *reinterpret_cast<const float2*>(xp + 6 * TK_);
    float2 x7 = *reinterpret_cast<const float2*>(xp + 7 * TK_);
    float l0 = lrow[0], l1 = lrow[1], l2 = lrow[2], l3 = lrow[3];
    float l4 = lrow[4], l5 = lrow[5], l6 = lrow[6], l7 = lrow[7];

    float a0, a1, a2, a3, a4, p3;
    a0 = (lane == 0) ? (l0 - EB8)                     : NEGF;
    a1 = (lane == 0) ? __builtin_fmaf(x0.x, K2, l0)   : NEGF;
    a2 = NEGF; a3 = NEGF; a4 = NEGF; p3 = NEGF;

#define STEP(i)                                                               \
    do {                                                                      \
        int t = t0 + (i);                                                     \
        float2 xv = x##i; float lv = l##i;                                    \
        int tp = min(t + 8, TQ_ - 1);                                         \
        x##i = *reinterpret_cast<const float2*>(xp + (size_t)tp * TK_);       \
        l##i = lrow[tp];                                                      \
        if (t >= 1 && t < q) {                                                \
            float e0 = __builtin_fmaf(xv.x, K2, lv);                          \
            float e1 = __builtin_fmaf(xv.y, K2, lv);                          \
            float eb = lv - EB8;                                              \
            float c01 = lae2_2(a0, p3);     /* old a0, prev-step p3 */        \
            float c12 = lae2_2(a2, a1);     /* old a2, a1 */                  \
            float n4  = lae2_2(a4, a3) + eb;/* old a4, a3 */                  \
            a0 = c01 + eb;                                                    \
            float n1 = lae2_2(a1, c01) + e0;                                  \
            a2 = c12 + eb;                                                    \
            a3 = lae2_2(a3, c12) + e1;                                        \
            a1 = n1; a4 = n4;                                                 \
            p3 = dpp_shr1_old(a3, NEGF);    /* consumed next step */          \
        }                                                                     \
    } while (0)

    for (int t0 = 0; t0 < q; t0 += 8) {
        STEP(0); STEP(1); STEP(2); STEP(3);
        STEP(4); STEP(5); STEP(6); STEP(7);
    }
#undef STEP

    // gather alpha[2k-1], alpha[2k] (log2 domain)
    int s1 = 2 * k - 1;
    int s2 = 2 * k;
    float e1v, e2v;
    {
        int l = s1 >> 2, r = s1 & 3;
        float c1 = __shfl(a1, l), c3 = __shfl(a3, l);
        e1v = (r == 1) ? c1 : c3;
    }
    if (s2 == 256) {
        e2v = __shfl(a4, 63);
    } else {
        int l = s2 >> 2, r = s2 & 3;
        float c0 = __shfl(a0, l), c2 = __shfl(a2, l);
        e2v = (r == 0) ? c0 : c2;
    }
    float nll = -lae2_2(e1v, e2v) * LN2;   // back to nats
    float loss = nll / (float)k;
    if (!(isfinite(loss) && loss < 1.0e8f)) loss = 0.0f;
    if (lane == 0) loss_out[n] = loss;
}

// ---------- Kernel 3: finalize ----------
__global__ __launch_bounds__(256) void fin_kernel(
    const float* __restrict__ nll, const int* __restrict__ alens,
    const int* __restrict__ step, const float* __restrict__ attn_losses,
    float* __restrict__ out)
{
    __shared__ float red[4];
    int tid = threadIdx.x;
    float s = 0.0f;
    for (int i = tid; i < B_ * T_TOK; i += 256) s += nll[i];
    #pragma unroll
    for (int off = 32; off > 0; off >>= 1) s += __shfl_xor(s, off);
    if ((tid & 63) == 0) red[tid >> 6] = s;
    __syncthreads();
    if (tid == 0) {
        float ce_sum = red[0] + red[1] + red[2] + red[3];
        int denom = 0;
        for (int b = 0; b < B_; b++) denom += min(alens[b], T_TOK);
        denom = max(denom, 1);
        float token = ce_sum / (float)denom;
        float a = 0.0f;
        for (int i = 0; i < NSEQ; i++) a += attn_losses[i];
        a *= (1.0f / NSEQ);
        if (step[0] <= 5000) a = 0.0f;
        out[0] = 1.5f * token + 10.0f * a;
        out[1] = a;
        out[2] = token;
    }
}

extern "C" void kernel_launch(void* const* d_in, const int* in_sizes, int n_in,
                              void* d_out, int out_size, void* d_ws, size_t ws_size,
                              hipStream_t stream)
{
    const float* logits  = (const float*)d_in[0];
    const float* attn    = (const float*)d_in[1];
    const int*   targets = (const int*)d_in[2];
    const int*   alens   = (const int*)d_in[3];
    const int*   slens   = (const int*)d_in[4];
    const int*   olens   = (const int*)d_in[5];
    const int*   step    = (const int*)d_in[6];
    float* out = (float*)d_out;
    float* ws  = (float*)d_ws;

    float* ws_attn = ws;            // [0..31]
    float* ws_lneg = ws + 64;       // [64 .. 64+25600)
    float* ws_nll  = ws + 25728;    // [25728 .. +8192)

    ce_kernel <<<dim3(B_ * T_TOK / 4), dim3(256), 0, stream>>>(logits, targets, alens, ws_nll);
    lse_kernel<<<dim3(TQ_ / 4, NSEQ),  dim3(256), 0, stream>>>(attn, slens, ws_lneg);
    rec_kernel<<<dim3(NSEQ),           dim3(64),  0, stream>>>(attn, ws_lneg, slens, olens, ws_attn);
    fin_kernel<<<dim3(1),              dim3(256), 0, stream>>>(ws_nll, alens, step, ws_attn, out);
}

// Round 6
// 396.617 us; speedup vs baseline: 1.2266x; 1.0173x over previous
//
#include <hip/hip_runtime.h>
#include <hip/hip_bf16.h>
#include <cstdint>
#include <cstddef>

#define V_TEXT   256
#define V_TOTAL  4352
#define V_AUDIO  4096
#define B_       8
#define H_       4
#define TQ_      800
#define TK_      128
#define T_TOK    1024
#define NSEQ     32
#define NEGF     (-1.0e9f)
#define K2       1.4426950408889634f   // 1/ln2
#define LN2      0.6931471805599453f
#define EB8      11.541560327111707f   // 8*K2
#define FNEGINF  (-3.0e38f)

// ---- DPP helpers (VALU cross-lane). ctrl must be a compile-time constant. ----
template <int CTRL>
__device__ __forceinline__ float dpp_mov(float x, float old) {
    return __int_as_float(__builtin_amdgcn_update_dpp(
        __float_as_int(old), __float_as_int(x), CTRL, 0xf, 0xf, false));
}
__device__ __forceinline__ float dpp_shr1_old(float x, float old) {
    return dpp_mov<0x138>(x, old);      // wave_shr:1
}
__device__ __forceinline__ float lane_bcast(float x, int lane) {
    return __int_as_float(__builtin_amdgcn_readlane(__float_as_int(x), lane));
}
__device__ __forceinline__ float wave_max(float x) {
    x = fmaxf(x, dpp_mov<0x111>(x, FNEGINF));
    x = fmaxf(x, dpp_mov<0x112>(x, FNEGINF));
    x = fmaxf(x, dpp_mov<0x114>(x, FNEGINF));
    x = fmaxf(x, dpp_mov<0x118>(x, FNEGINF));
    x = fmaxf(x, dpp_mov<0x142>(x, FNEGINF));
    x = fmaxf(x, dpp_mov<0x143>(x, FNEGINF));
    return lane_bcast(x, 63);
}
__device__ __forceinline__ float wave_sum(float x) {
    x += dpp_mov<0x111>(x, 0.0f);
    x += dpp_mov<0x112>(x, 0.0f);
    x += dpp_mov<0x114>(x, 0.0f);
    x += dpp_mov<0x118>(x, 0.0f);
    x += dpp_mov<0x142>(x, 0.0f);
    x += dpp_mov<0x143>(x, 0.0f);
    return lane_bcast(x, 63);
}

// base-2 logaddexp (inputs already in log2 domain)
__device__ __forceinline__ float lae2_2(float a, float b) {
    float m = fmaxf(a, b);
    float d = fminf(a, b) - m;
    return m + __builtin_log2f(1.0f + __builtin_exp2f(d));
}

// ---------- Kernel 1: per-row CE nll, one wave per row ----------
__global__ __launch_bounds__(256) void ce_kernel(
    const float* __restrict__ logits, const int* __restrict__ targets,
    const int* __restrict__ alens, float* __restrict__ nll_out)
{
    int w = threadIdx.x >> 6, lane = threadIdx.x & 63;
    int row = blockIdx.x * 4 + w;
    const float* p = logits + (size_t)row * V_TOTAL + V_TEXT;

    float4 v0 = *reinterpret_cast<const float4*>(p + lane * 4);
    float4 v1 = *reinterpret_cast<const float4*>(p + lane * 4 + 1024);
    float4 v2 = *reinterpret_cast<const float4*>(p + lane * 4 + 2048);
    float4 v3 = *reinterpret_cast<const float4*>(p + lane * 4 + 3072);
    int tg = targets[row];

    float m = fmaxf(fmaxf(fmaxf(v0.x, v0.y), fmaxf(v0.z, v0.w)),
                    fmaxf(fmaxf(v1.x, v1.y), fmaxf(v1.z, v1.w)));
    m = fmaxf(m, fmaxf(fmaxf(v2.x, v2.y), fmaxf(v2.z, v2.w)));
    m = fmaxf(m, fmaxf(fmaxf(v3.x, v3.y), fmaxf(v3.z, v3.w)));
    m = wave_max(m);

    float mn = -m * K2;
    float s =
      __builtin_exp2f(__builtin_fmaf(v0.x,K2,mn)) + __builtin_exp2f(__builtin_fmaf(v0.y,K2,mn))
    + __builtin_exp2f(__builtin_fmaf(v0.z,K2,mn)) + __builtin_exp2f(__builtin_fmaf(v0.w,K2,mn))
    + __builtin_exp2f(__builtin_fmaf(v1.x,K2,mn)) + __builtin_exp2f(__builtin_fmaf(v1.y,K2,mn))
    + __builtin_exp2f(__builtin_fmaf(v1.z,K2,mn)) + __builtin_exp2f(__builtin_fmaf(v1.w,K2,mn))
    + __builtin_exp2f(__builtin_fmaf(v2.x,K2,mn)) + __builtin_exp2f(__builtin_fmaf(v2.y,K2,mn))
    + __builtin_exp2f(__builtin_fmaf(v2.z,K2,mn)) + __builtin_exp2f(__builtin_fmaf(v2.w,K2,mn))
    + __builtin_exp2f(__builtin_fmaf(v3.x,K2,mn)) + __builtin_exp2f(__builtin_fmaf(v3.y,K2,mn))
    + __builtin_exp2f(__builtin_fmaf(v3.z,K2,mn)) + __builtin_exp2f(__builtin_fmaf(v3.w,K2,mn));
    s = wave_sum(s);

    if (lane == 0) {
        float lse = m + __builtin_log2f(s) * LN2;
        int b = row >> 10, t = row & (T_TOK - 1);
        bool valid = (t < alens[b]) && (tg != -100);
        float nll = 0.0f;
        if (valid) {
            int idx = min(max(tg - V_TEXT, 0), V_AUDIO - 1);
            nll = lse - p[idx];
        }
        nll_out[row] = nll;
    }
}

// ---------- Kernel 2a: per-(n,t) masked logsumexp; outputs Lneg = -lse*K2 ----------
__global__ __launch_bounds__(256) void lse_kernel(
    const float* __restrict__ attn, const int* __restrict__ src_lens,
    float* __restrict__ lneg_out)
{
    int w = threadIdx.x >> 6, lane = threadIdx.x & 63;
    int t = blockIdx.x * 4 + w;
    int n = blockIdx.y;
    int k = min(src_lens[n >> 2], TK_);

    const float2 x = *reinterpret_cast<const float2*>(
        attn + ((size_t)n * TQ_ + t) * TK_ + 2 * lane);
    float xx = x.x * K2, xy = x.y * K2;
    int j0 = 2 * lane + 1, j1 = 2 * lane + 2;

    float m = (lane == 0) ? -EB8 : FNEGINF;
    if (j0 <= k) m = fmaxf(m, xx);
    if (j1 <= k) m = fmaxf(m, xy);
    m = wave_max(m);

    float s = (lane == 0) ? __builtin_exp2f(-EB8 - m) : 0.0f;
    if (j0 <= k) s += __builtin_exp2f(xx - m);
    if (j1 <= k) s += __builtin_exp2f(xy - m);
    s = wave_sum(s);

    if (lane == 0) lneg_out[n * TQ_ + t] = -(m + __builtin_log2f(s));
}

// ---------- Kernel 2b: CTC forward recursion, one wave per sequence ----------
// Normalization-deferral: beta_t = alpha_t - C_t with C_t = sum lneg; the
// per-step lse term telescopes out, so the K-loop touches ONLY the attn
// float2 prefetch (vector loads, in-order vmcnt) -- no SMEM/uniform loads
// that would force lgkmcnt(0) drains. 16-deep register prefetch.
__global__ __launch_bounds__(64) void rec_kernel(
    const float* __restrict__ attn, const float* __restrict__ lneg,
    const int* __restrict__ src_lens, const int* __restrict__ out_lens,
    float* __restrict__ loss_out)
{
    int n = blockIdx.x;
    int lane = threadIdx.x;
    int k = min(src_lens[n >> 2], TK_);
    int q = min(out_lens[n >> 2], TQ_);
    const float* xp = attn + (size_t)n * TQ_ * TK_ + 2 * lane;
    const float* lrow = lneg + n * TQ_;

    // C = sum_{t<q} lneg[t]  (parallel, off the critical path)
    float Cs = 0.0f;
    for (int i = lane; i < q; i += 64) Cs += lrow[i];
    Cs = wave_sum(Cs);

    // 16-deep preload, named scalars only
    float2 x0  = *reinterpret_cast<const float2*>(xp +  0 * TK_);
    float2 x1  = *reinterpret_cast<const float2*>(xp +  1 * TK_);
    float2 x2  = *reinterpret_cast<const float2*>(xp +  2 * TK_);
    float2 x3  = *reinterpret_cast<const float2*>(xp +  3 * TK_);
    float2 x4  = *reinterpret_cast<const float2*>(xp +  4 * TK_);
    float2 x5  = *reinterpret_cast<const float2*>(xp +  5 * TK_);
    float2 x6  = *reinterpret_cast<const float2*>(xp +  6 * TK_);
    float2 x7  = *reinterpret_cast<const float2*>(xp +  7 * TK_);
    float2 x8  = *reinterpret_cast<const float2*>(xp +  8 * TK_);
    float2 x9  = *reinterpret_cast<const float2*>(xp +  9 * TK_);
    float2 x10 = *reinterpret_cast<const float2*>(xp + 10 * TK_);
    float2 x11 = *reinterpret_cast<const float2*>(xp + 11 * TK_);
    float2 x12 = *reinterpret_cast<const float2*>(xp + 12 * TK_);
    float2 x13 = *reinterpret_cast<const float2*>(xp + 13 * TK_);
    float2 x14 = *reinterpret_cast<const float2*>(xp + 14 * TK_);
    float2 x15 = *reinterpret_cast<const float2*>(xp + 15 * TK_);

    // beta-domain init (t=0): beta[0] = -8*K2, beta[1] = x*K2
    float a0, a1, a2, a3, a4, p3;
    a0 = (lane == 0) ? -EB8        : NEGF;
    a1 = (lane == 0) ? (x0.x * K2) : NEGF;
    a2 = NEGF; a3 = NEGF; a4 = NEGF; p3 = NEGF;

#define STEP(i)                                                               \
    do {                                                                      \
        int t = t0 + (i);                                                     \
        float2 xv = x##i;                                                     \
        int tp = min(t + 16, TQ_ - 1);                                        \
        x##i = *reinterpret_cast<const float2*>(xp + (size_t)tp * TK_);       \
        if (t >= 1 && t < q) {                                                \
            float e0 = xv.x * K2;                                             \
            float e1 = xv.y * K2;                                             \
            float c01 = lae2_2(a0, p3);                                       \
            float c12 = lae2_2(a2, a1);                                       \
            float n4  = lae2_2(a4, a3) - EB8;                                 \
            a0 = c01 - EB8;                                                   \
            float n1 = lae2_2(a1, c01) + e0;                                  \
            a2 = c12 - EB8;                                                   \
            a3 = lae2_2(a3, c12) + e1;                                        \
            a1 = n1; a4 = n4;                                                 \
            p3 = dpp_shr1_old(a3, NEGF);                                      \
        }                                                                     \
    } while (0)

    for (int t0 = 0; t0 < q; t0 += 16) {
        STEP(0);  STEP(1);  STEP(2);  STEP(3);
        STEP(4);  STEP(5);  STEP(6);  STEP(7);
        STEP(8);  STEP(9);  STEP(10); STEP(11);
        STEP(12); STEP(13); STEP(14); STEP(15);
    }
#undef STEP

    // gather beta[2k-1], beta[2k]; alpha = beta + C
    int s1 = 2 * k - 1;
    int s2 = 2 * k;
    float e1v, e2v;
    {
        int l = s1 >> 2, r = s1 & 3;
        float c1 = __shfl(a1, l), c3 = __shfl(a3, l);
        e1v = (r == 1) ? c1 : c3;
    }
    if (s2 == 256) {
        e2v = __shfl(a4, 63);
    } else {
        int l = s2 >> 2, r = s2 & 3;
        float c0 = __shfl(a0, l), c2 = __shfl(a2, l);
        e2v = (r == 0) ? c0 : c2;
    }
    float nll = -(lae2_2(e1v, e2v) + Cs) * LN2;   // back to nats
    float loss = nll / (float)k;
    if (!(isfinite(loss) && loss < 1.0e8f)) loss = 0.0f;
    if (lane == 0) loss_out[n] = loss;
}

// ---------- Kernel 3: finalize ----------
__global__ __launch_bounds__(256) void fin_kernel(
    const float* __restrict__ nll, const int* __restrict__ alens,
    const int* __restrict__ step, const float* __restrict__ attn_losses,
    float* __restrict__ out)
{
    __shared__ float red[4];
    int tid = threadIdx.x;
    float s = 0.0f;
    for (int i = tid; i < B_ * T_TOK; i += 256) s += nll[i];
    #pragma unroll
    for (int off = 32; off > 0; off >>= 1) s += __shfl_xor(s, off);
    if ((tid & 63) == 0) red[tid >> 6] = s;
    __syncthreads();
    if (tid == 0) {
        float ce_sum = red[0] + red[1] + red[2] + red[3];
        int denom = 0;
        for (int b = 0; b < B_; b++) denom += min(alens[b], T_TOK);
        denom = max(denom, 1);
        float token = ce_sum / (float)denom;
        float a = 0.0f;
        for (int i = 0; i < NSEQ; i++) a += attn_losses[i];
        a *= (1.0f / NSEQ);
        if (step[0] <= 5000) a = 0.0f;
        out[0] = 1.5f * token + 10.0f * a;
        out[1] = a;
        out[2] = token;
    }
}

extern "C" void kernel_launch(void* const* d_in, const int* in_sizes, int n_in,
                              void* d_out, int out_size, void* d_ws, size_t ws_size,
                              hipStream_t stream)
{
    const float* logits  = (const float*)d_in[0];
    const float* attn    = (const float*)d_in[1];
    const int*   targets = (const int*)d_in[2];
    const int*   alens   = (const int*)d_in[3];
    const int*   slens   = (const int*)d_in[4];
    const int*   olens   = (const int*)d_in[5];
    const int*   step    = (const int*)d_in[6];
    float* out = (float*)d_out;
    float* ws  = (float*)d_ws;

    float* ws_attn = ws;            // [0..31]
    float* ws_lneg = ws + 64;       // [64 .. 64+25600)
    float* ws_nll  = ws + 25728;    // [25728 .. +8192)

    ce_kernel <<<dim3(B_ * T_TOK / 4), dim3(256), 0, stream>>>(logits, targets, alens, ws_nll);
    lse_kernel<<<dim3(TQ_ / 4, NSEQ),  dim3(256), 0, stream>>>(attn, slens, ws_lneg);
    rec_kernel<<<dim3(NSEQ),           dim3(64),  0, stream>>>(attn, ws_lneg, slens, olens, ws_attn);
    fin_kernel<<<dim3(1),              dim3(256), 0, stream>>>(ws_nll, alens, step, ws_attn, out);
}

// Round 7
// 361.858 us; speedup vs baseline: 1.3444x; 1.0961x over previous
//
#include <hip/hip_runtime.h>
#include <hip/hip_bf16.h>
#include <cstdint>
#include <cstddef>

#define V_TEXT   256
#define V_TOTAL  4352
#define V_AUDIO  4096
#define B_       8
#define H_       4
#define TQ_      800
#define TK_      128
#define T_TOK    1024
#define NSEQ     32
#define NEGF     (-1.0e9f)
#define K2       1.4426950408889634f   // 1/ln2
#define LN2      0.6931471805599453f
#define EB8      11.541560327111707f   // 8*K2
#define FNEGINF  (-3.0e38f)
#define CHK      60                    // timesteps per LDS chunk
#define NCH      14                    // ceil(800/60)

// ---- DPP helpers (ctrl must be a compile-time constant) ----
template <int CTRL>
__device__ __forceinline__ float dpp_mov(float x, float old) {
    return __int_as_float(__builtin_amdgcn_update_dpp(
        __float_as_int(old), __float_as_int(x), CTRL, 0xf, 0xf, false));
}
__device__ __forceinline__ float dpp_shr1_old(float x, float old) {
    return dpp_mov<0x138>(x, old);      // wave_shr:1
}
__device__ __forceinline__ float lane_bcast(float x, int lane) {
    return __int_as_float(__builtin_amdgcn_readlane(__float_as_int(x), lane));
}
__device__ __forceinline__ float wave_max(float x) {
    x = fmaxf(x, dpp_mov<0x111>(x, FNEGINF));
    x = fmaxf(x, dpp_mov<0x112>(x, FNEGINF));
    x = fmaxf(x, dpp_mov<0x114>(x, FNEGINF));
    x = fmaxf(x, dpp_mov<0x118>(x, FNEGINF));
    x = fmaxf(x, dpp_mov<0x142>(x, FNEGINF));
    x = fmaxf(x, dpp_mov<0x143>(x, FNEGINF));
    return lane_bcast(x, 63);
}
__device__ __forceinline__ float wave_sum(float x) {
    x += dpp_mov<0x111>(x, 0.0f);
    x += dpp_mov<0x112>(x, 0.0f);
    x += dpp_mov<0x114>(x, 0.0f);
    x += dpp_mov<0x118>(x, 0.0f);
    x += dpp_mov<0x142>(x, 0.0f);
    x += dpp_mov<0x143>(x, 0.0f);
    return lane_bcast(x, 63);
}

// base-2 logaddexp (inputs in log2 domain)
__device__ __forceinline__ float lae2_2(float a, float b) {
    float m = fmaxf(a, b);
    float d = fminf(a, b) - m;
    return m + __builtin_log2f(1.0f + __builtin_exp2f(d));
}

// ---------- Kernel 1: per-row CE nll, one wave per row ----------
__global__ __launch_bounds__(256) void ce_kernel(
    const float* __restrict__ logits, const int* __restrict__ targets,
    const int* __restrict__ alens, float* __restrict__ nll_out)
{
    int w = threadIdx.x >> 6, lane = threadIdx.x & 63;
    int row = blockIdx.x * 4 + w;
    const float* p = logits + (size_t)row * V_TOTAL + V_TEXT;

    float4 v0 = *reinterpret_cast<const float4*>(p + lane * 4);
    float4 v1 = *reinterpret_cast<const float4*>(p + lane * 4 + 1024);
    float4 v2 = *reinterpret_cast<const float4*>(p + lane * 4 + 2048);
    float4 v3 = *reinterpret_cast<const float4*>(p + lane * 4 + 3072);
    int tg = targets[row];

    float m = fmaxf(fmaxf(fmaxf(v0.x, v0.y), fmaxf(v0.z, v0.w)),
                    fmaxf(fmaxf(v1.x, v1.y), fmaxf(v1.z, v1.w)));
    m = fmaxf(m, fmaxf(fmaxf(v2.x, v2.y), fmaxf(v2.z, v2.w)));
    m = fmaxf(m, fmaxf(fmaxf(v3.x, v3.y), fmaxf(v3.z, v3.w)));
    m = wave_max(m);

    float mn = -m * K2;
    float s =
      __builtin_exp2f(__builtin_fmaf(v0.x,K2,mn)) + __builtin_exp2f(__builtin_fmaf(v0.y,K2,mn))
    + __builtin_exp2f(__builtin_fmaf(v0.z,K2,mn)) + __builtin_exp2f(__builtin_fmaf(v0.w,K2,mn))
    + __builtin_exp2f(__builtin_fmaf(v1.x,K2,mn)) + __builtin_exp2f(__builtin_fmaf(v1.y,K2,mn))
    + __builtin_exp2f(__builtin_fmaf(v1.z,K2,mn)) + __builtin_exp2f(__builtin_fmaf(v1.w,K2,mn))
    + __builtin_exp2f(__builtin_fmaf(v2.x,K2,mn)) + __builtin_exp2f(__builtin_fmaf(v2.y,K2,mn))
    + __builtin_exp2f(__builtin_fmaf(v2.z,K2,mn)) + __builtin_exp2f(__builtin_fmaf(v2.w,K2,mn))
    + __builtin_exp2f(__builtin_fmaf(v3.x,K2,mn)) + __builtin_exp2f(__builtin_fmaf(v3.y,K2,mn))
    + __builtin_exp2f(__builtin_fmaf(v3.z,K2,mn)) + __builtin_exp2f(__builtin_fmaf(v3.w,K2,mn));
    s = wave_sum(s);

    if (lane == 0) {
        float lse = m + __builtin_log2f(s) * LN2;
        int b = row >> 10, t = row & (T_TOK - 1);
        bool valid = (t < alens[b]) && (tg != -100);
        float nll = 0.0f;
        if (valid) {
            int idx = min(max(tg - V_TEXT, 0), V_AUDIO - 1);
            nll = lse - p[idx];
        }
        nll_out[row] = nll;
    }
}

// ---------- Kernel 2a: per-(n,t) masked logsumexp; outputs Lneg = -lse*K2 ----------
__global__ __launch_bounds__(256) void lse_kernel(
    const float* __restrict__ attn, const int* __restrict__ src_lens,
    float* __restrict__ lneg_out)
{
    int w = threadIdx.x >> 6, lane = threadIdx.x & 63;
    int t = blockIdx.x * 4 + w;
    int n = blockIdx.y;
    int k = min(src_lens[n >> 2], TK_);

    const float2 x = *reinterpret_cast<const float2*>(
        attn + ((size_t)n * TQ_ + t) * TK_ + 2 * lane);
    float xx = x.x * K2, xy = x.y * K2;
    int j0 = 2 * lane + 1, j1 = 2 * lane + 2;

    float m = (lane == 0) ? -EB8 : FNEGINF;
    if (j0 <= k) m = fmaxf(m, xx);
    if (j1 <= k) m = fmaxf(m, xy);
    m = wave_max(m);

    float s = (lane == 0) ? __builtin_exp2f(-EB8 - m) : 0.0f;
    if (j0 <= k) s += __builtin_exp2f(xx - m);
    if (j1 <= k) s += __builtin_exp2f(xy - m);
    s = wave_sum(s);

    if (lane == 0) lneg_out[n * TQ_ + t] = -(m + __builtin_log2f(s));
}

// ---------- Kernel 2b: CTC recursion, producer/consumer waves via LDS ----------
// Block = 2 waves. Wave 1 streams 60-step chunks of attn (pre-scaled by K2)
// into double-buffered LDS; wave 0 runs the beta-recursion (normalization
// telescoped out) reading float2 from LDS with a 4-deep named prefetch.
// DS completes in-order -> fine-grained lgkmcnt; no global latency on chain.
__global__ __launch_bounds__(128) void rec_kernel(
    const float* __restrict__ attn, const float* __restrict__ lneg,
    const int* __restrict__ src_lens, const int* __restrict__ out_lens,
    float* __restrict__ loss_out)
{
    __shared__ float buf[2][CHK][TK_];   // 61440 B
    int n = blockIdx.x;
    int tid = threadIdx.x;
    int wid = tid >> 6, lane = tid & 63;
    int k = min(src_lens[n >> 2], TK_);
    int q = min(out_lens[n >> 2], TQ_);
    const float* abase = attn + (size_t)n * TQ_ * TK_;

    float Cs = 0.0f;
    float a0 = NEGF, a1 = NEGF, a2 = NEGF, a3 = NEGF, a4 = NEGF, p3 = NEGF;

    if (wid == 1) {
        // producer: preload chunk 0 (rows 0..59), pre-scaled by K2
        int half = lane >> 5, col = (lane & 31) * 4;
        #pragma unroll 6
        for (int i = 0; i < CHK / 2; i++) {
            int r = 2 * i + half;
            float4 v = *reinterpret_cast<const float4*>(abase + (size_t)r * TK_ + col);
            *reinterpret_cast<float4*>(&buf[0][r][col]) =
                make_float4(v.x * K2, v.y * K2, v.z * K2, v.w * K2);
        }
    } else {
        // consumer: Cs = sum_{t<q} lneg[t] (off the critical path)
        const float* lrow = lneg + n * TQ_;
        for (int i = lane; i < q; i += 64) Cs += lrow[i];
        Cs = wave_sum(Cs);
    }
    __syncthreads();

    if (wid == 0) {                      // t=0 init (beta domain, log2 units)
        a0 = (lane == 0) ? -EB8 : NEGF;
        a1 = (lane == 0) ? buf[0][0][0] : NEGF;   // already *K2
    }

    for (int c = 0; c < NCH; c++) {
        if (wid == 1) {
            if (c + 1 < NCH) {           // load chunk c+1 into buf[(c+1)&1]
                int g0 = (c + 1) * CHK;
                int half = lane >> 5, col = (lane & 31) * 4;
                float* db = &buf[(c + 1) & 1][0][0];
                #pragma unroll 6
                for (int i = 0; i < CHK / 2; i++) {
                    int r = 2 * i + half;
                    int rg = min(g0 + r, TQ_ - 1);   // clamp: no OOB past attn
                    float4 v = *reinterpret_cast<const float4*>(abase + (size_t)rg * TK_ + col);
                    *reinterpret_cast<float4*>(db + r * TK_ + col) =
                        make_float4(v.x * K2, v.y * K2, v.z * K2, v.w * K2);
                }
            }
        } else {
            const float* lb = &buf[c & 1][0][2 * lane];
            int lim = min(CHK, q - c * CHK);
            int ts = (c == 0) ? 1 : 0;
            if (ts < lim) {
#define LD(j) (*reinterpret_cast<const float2*>(lb + min((j), CHK - 1) * TK_))
#define SSTEP(xv)                                                             \
    do {                                                                      \
        float c01 = lae2_2(a0, p3);                                           \
        float c12 = lae2_2(a2, a1);                                           \
        float n4  = lae2_2(a4, a3) - EB8;                                     \
        a0 = c01 - EB8;                                                       \
        float n1 = lae2_2(a1, c01) + xv.x;                                    \
        a2 = c12 - EB8;                                                       \
        a3 = lae2_2(a3, c12) + xv.y;                                          \
        a1 = n1; a4 = n4;                                                     \
        p3 = dpp_shr1_old(a3, NEGF);                                          \
    } while (0)
                float2 A = LD(ts), Bv = LD(ts + 1), Cv = LD(ts + 2), Dv = LD(ts + 3);
                for (; ts + 4 <= lim; ts += 4) {
                    float2 nA = LD(ts + 4), nB = LD(ts + 5), nC = LD(ts + 6), nD = LD(ts + 7);
                    SSTEP(A); SSTEP(Bv); SSTEP(Cv); SSTEP(Dv);
                    A = nA; Bv = nB; Cv = nC; Dv = nD;
                }
                for (; ts < lim; ts++) { SSTEP(A); A = Bv; Bv = Cv; Cv = Dv; }
#undef SSTEP
#undef LD
            }
        }
        __syncthreads();
    }

    if (wid == 0) {
        int s1 = 2 * k - 1, s2 = 2 * k;
        float e1v, e2v;
        {
            int l = s1 >> 2, r = s1 & 3;
            float c1 = __shfl(a1, l), c3 = __shfl(a3, l);
            e1v = (r == 1) ? c1 : c3;
        }
        if (s2 == 256) {
            e2v = __shfl(a4, 63);
        } else {
            int l = s2 >> 2, r = s2 & 3;
            float c0 = __shfl(a0, l), c2 = __shfl(a2, l);
            e2v = (r == 0) ? c0 : c2;
        }
        float nll = -(lae2_2(e1v, e2v) + Cs) * LN2;
        float loss = nll / (float)k;
        if (!(isfinite(loss) && loss < 1.0e8f)) loss = 0.0f;
        if (lane == 0) loss_out[n] = loss;
    }
}

// ---------- Kernel 3: finalize ----------
__global__ __launch_bounds__(256) void fin_kernel(
    const float* __restrict__ nll, const int* __restrict__ alens,
    const int* __restrict__ step, const float* __restrict__ attn_losses,
    float* __restrict__ out)
{
    __shared__ float red[4];
    int tid = threadIdx.x;
    float s = 0.0f;
    for (int i = tid; i < B_ * T_TOK; i += 256) s += nll[i];
    #pragma unroll
    for (int off = 32; off > 0; off >>= 1) s += __shfl_xor(s, off);
    if ((tid & 63) == 0) red[tid >> 6] = s;
    __syncthreads();
    if (tid == 0) {
        float ce_sum = red[0] + red[1] + red[2] + red[3];
        int denom = 0;
        for (int b = 0; b < B_; b++) denom += min(alens[b], T_TOK);
        denom = max(denom, 1);
        float token = ce_sum / (float)denom;
        float a = 0.0f;
        for (int i = 0; i < NSEQ; i++) a += attn_losses[i];
        a *= (1.0f / NSEQ);
        if (step[0] <= 5000) a = 0.0f;
        out[0] = 1.5f * token + 10.0f * a;
        out[1] = a;
        out[2] = token;
    }
}

extern "C" void kernel_launch(void* const* d_in, const int* in_sizes, int n_in,
                              void* d_out, int out_size, void* d_ws, size_t ws_size,
                              hipStream_t stream)
{
    const float* logits  = (const float*)d_in[0];
    const float* attn    = (const float*)d_in[1];
    const int*   targets = (const int*)d_in[2];
    const int*   alens   = (const int*)d_in[3];
    const int*   slens   = (const int*)d_in[4];
    const int*   olens   = (const int*)d_in[5];
    const int*   step    = (const int*)d_in[6];
    float* out = (float*)d_out;
    float* ws  = (float*)d_ws;

    float* ws_attn = ws;            // [0..31]
    float* ws_lneg = ws + 64;       // [64 .. 64+25600)
    float* ws_nll  = ws + 25728;    // [25728 .. +8192)

    ce_kernel <<<dim3(B_ * T_TOK / 4), dim3(256), 0, stream>>>(logits, targets, alens, ws_nll);
    lse_kernel<<<dim3(TQ_ / 4, NSEQ),  dim3(256), 0, stream>>>(attn, slens, ws_lneg);
    rec_kernel<<<dim3(NSEQ),           dim3(128), 0, stream>>>(attn, ws_lneg, slens, olens, ws_attn);
    fin_kernel<<<dim3(1),              dim3(256), 0, stream>>>(ws_nll, alens, step, ws_attn, out);
}